// Round 1
// baseline (610.414 us; speedup 1.0000x reference)
//
#include <hip/hip_runtime.h>
#include <math.h>

#define T_LEN 2048
#define K_ST  48

// One wave (64 lanes) per batch element. Lane j (j<48) owns state column j:
//  - et[i] = exp(trans[i][j]) held in 48 VGPRs (constant across the scan)
//  - s     = exp(alpha_j - M)   (probability-domain state, lane-0 normalized)
//  - M     = wave-uniform log-scale accumulator
// Per step: d_j = sum_i s_i*et[i] via readlane broadcasts + FMA;
//           e_j = d_j * exp(logit_t_j); s'_j = e_j / e_0; M += log(e_0).
__global__ __launch_bounds__(64) void crf_fwd_kernel(
    const float* __restrict__ logits,      // [B, T, K]
    const float* __restrict__ trans,       // [K, K]
    const int*   __restrict__ targets,     // [B, T]
    const int*   __restrict__ lens,        // [B]
    float*       __restrict__ out)         // [B]
{
    const int b    = blockIdx.x;
    const int lane = threadIdx.x;          // 0..63
    const int jj   = (lane < K_ST) ? lane : 0;
    const int L    = lens[b];

    __shared__ float s_trans[K_ST * K_ST];
    for (int k = lane; k < K_ST * K_ST; k += 64)
        s_trans[k] = trans[k];

    // Per-lane transition column, exponentiated once.
    float et[K_ST];
    #pragma unroll
    for (int i = 0; i < K_ST; ++i)
        et[i] = __expf(trans[i * K_ST + jj]);

    __syncthreads();

    const float* lg_b = logits  + (size_t)b * T_LEN * K_ST;
    const int*   tg_b = targets + (size_t)b * T_LEN;

    // ---- unary + binary scores: parallel over t across the wave ----
    float ub = 0.f;
    for (int t = lane; t < T_LEN; t += 64) {
        if (t < L) {
            int tg = tg_b[t];
            ub += lg_b[t * K_ST + tg];
            if (t >= 1) {
                int tp = tg_b[t - 1];
                ub += s_trans[tp * K_ST + tg];
            }
        }
    }
    #pragma unroll
    for (int d = 32; d >= 1; d >>= 1)
        ub += __shfl_xor(ub, d, 64);

    // ---- forward scan (serial chain) ----
    float log_norm = 0.f;
    if (L > 0) {
        float a0 = lg_b[jj];
        float M  = __uint_as_float(__builtin_amdgcn_readlane(__float_as_uint(a0), 0));
        float s  = (lane < K_ST) ? __expf(a0 - M) : 0.f;

        float lg_next = lg_b[K_ST + jj];   // prefetch row t=1 (always in-bounds)
        for (int t = 1; t < L; ++t) {
            float lg = lg_next;
            lg_next  = lg_b[(t + 1) * K_ST + jj];   // t+1 <= 2047: in-bounds
            float eL = __expf(lg);                  // off-chain

            float acc0 = 0.f, acc1 = 0.f, acc2 = 0.f, acc3 = 0.f;
            #pragma unroll
            for (int i = 0; i < K_ST; i += 4) {
                float s0 = __uint_as_float(__builtin_amdgcn_readlane(__float_as_uint(s), i    ));
                float s1 = __uint_as_float(__builtin_amdgcn_readlane(__float_as_uint(s), i + 1));
                float s2 = __uint_as_float(__builtin_amdgcn_readlane(__float_as_uint(s), i + 2));
                float s3 = __uint_as_float(__builtin_amdgcn_readlane(__float_as_uint(s), i + 3));
                acc0 = fmaf(s0, et[i    ], acc0);
                acc1 = fmaf(s1, et[i + 1], acc1);
                acc2 = fmaf(s2, et[i + 2], acc2);
                acc3 = fmaf(s3, et[i + 3], acc3);
            }
            float dsum = (acc0 + acc1) + (acc2 + acc3);
            float e = dsum * eL;
            float r = __uint_as_float(__builtin_amdgcn_readlane(__float_as_uint(e), 0));
            float rr = __builtin_amdgcn_rcpf(r);
            s = e * rr;
            M += __logf(r);                          // off-chain (independent add chain)
        }

        float ssum = (lane < K_ST) ? s : 0.f;
        #pragma unroll
        for (int d = 32; d >= 1; d >>= 1)
            ssum += __shfl_xor(ssum, d, 64);
        log_norm = M + __logf(ssum);
    }

    if (lane == 0) out[b] = ub - log_norm;
}

extern "C" void kernel_launch(void* const* d_in, const int* in_sizes, int n_in,
                              void* d_out, int out_size, void* d_ws, size_t ws_size,
                              hipStream_t stream) {
    const float* logits  = (const float*)d_in[0];   // [256, 2048, 48]
    const float* trans   = (const float*)d_in[1];   // [48, 48]
    const int*   targets = (const int*)  d_in[2];   // [256, 2048]
    const int*   lens    = (const int*)  d_in[3];   // [256]
    float*       out     = (float*)d_out;           // [256]

    const int B = in_sizes[3];
    crf_fwd_kernel<<<B, 64, 0, stream>>>(logits, trans, targets, lens, out);
}

// Round 3
// 483.686 us; speedup vs baseline: 1.2620x; 1.2620x over previous
//
#include <hip/hip_runtime.h>
#include <math.h>

#define T_LEN 2048
#define K_ST  48

// readlane of a float (uniform result -> SGPR)
__device__ __forceinline__ float rlf(float x, int l) {
    return __uint_as_float((unsigned)__builtin_amdgcn_readlane((int)__float_as_uint(x), l));
}

// One wave (64 lanes) per batch element. Lane j (j<48) owns state column j:
//  - et[i] = exp(trans[i][j]) held in 48 VGPRs (constant across the scan)
//  - s     = exp(alpha_j - M)  (probability-domain state, lane-0 normalized each step)
//  - M     = wave-uniform log-scale accumulator
// Fixed 2048-step loop, 8-unrolled, 8-deep register prefetch of logit rows
// (statically indexed pf[] -> stays in VGPRs). State at t == L-1 captured via
// cndmask; steps beyond L are statistically identical junk, discarded.
__global__ __launch_bounds__(64) void crf_fwd_kernel(
    const float* __restrict__ logits,      // [B, T, K]
    const float* __restrict__ trans,       // [K, K]
    const int*   __restrict__ targets,     // [B, T]
    const int*   __restrict__ lens,        // [B]
    float*       __restrict__ out)         // [B]
{
    const int b    = blockIdx.x;
    const int lane = threadIdx.x;          // 0..63
    const int jj   = (lane < K_ST) ? lane : 0;
    const int L    = lens[b];

    __shared__ float s_trans[K_ST * K_ST];
    for (int k = lane; k < K_ST * K_ST; k += 64)
        s_trans[k] = trans[k];

    // Per-lane transition column, exponentiated once.
    float et[K_ST];
    #pragma unroll
    for (int i = 0; i < K_ST; ++i)
        et[i] = __expf(trans[i * K_ST + jj]);

    __syncthreads();

    const float* lg_b = logits  + (size_t)b * T_LEN * K_ST;
    const int*   tg_b = targets + (size_t)b * T_LEN;

    // ---- unary + binary scores: parallel over t across the wave ----
    float ub = 0.f;
    #pragma unroll 4
    for (int t = lane; t < T_LEN; t += 64) {
        if (t < L) {
            int tg = tg_b[t];
            ub += lg_b[t * K_ST + tg];
            if (t >= 1) {
                int tp = tg_b[t - 1];
                ub += s_trans[tp * K_ST + tg];
            }
        }
    }
    #pragma unroll
    for (int d = 32; d >= 1; d >>= 1)
        ub += __shfl_xor(ub, d, 64);

    // ---- forward scan (serial chain), fixed 2048 steps ----
    float a0 = lg_b[jj];
    float M  = rlf(a0, 0);
    float s  = (lane < K_ST) ? __expf(a0 - M) : 0.f;
    float sC = s;          // captured (pre-renorm) state at t = L-1
    float MC = M;
    const int Lm1 = L - 1;

    // 8-deep prefetch of logit rows 1..8
    float pf[8];
    #pragma unroll
    for (int u = 0; u < 8; ++u)
        pf[u] = lg_b[(1 + u) * K_ST + jj];

    #pragma unroll 1
    for (int c = 0; c < 256; ++c) {
        #pragma unroll
        for (int u = 0; u < 8; ++u) {
            const int t = 1 + c * 8 + u;            // 1..2048 (2048 = junk step)
            float lg = pf[u];
            int nrow = t + 8; if (nrow > T_LEN - 1) nrow = T_LEN - 1;  // clamped
            pf[u] = lg_b[nrow * K_ST + jj];
            float eL = __expf(lg);                  // off-chain

            float ac0 = 0.f, ac1 = 0.f, ac2 = 0.f, ac3 = 0.f;
            #pragma unroll
            for (int i = 0; i < K_ST; i += 4) {
                float s0 = rlf(s, i    );
                float s1 = rlf(s, i + 1);
                float s2 = rlf(s, i + 2);
                float s3 = rlf(s, i + 3);
                ac0 = fmaf(s0, et[i    ], ac0);
                ac1 = fmaf(s1, et[i + 1], ac1);
                ac2 = fmaf(s2, et[i + 2], ac2);
                ac3 = fmaf(s3, et[i + 3], ac3);
            }
            float dsum = (ac0 + ac1) + (ac2 + ac3);
            float e = dsum * eL;

            // capture at t == L-1 (pre-renorm state + pre-update M)
            bool cap = (t == Lm1);
            sC = cap ? e : sC;
            MC = cap ? M : MC;

            // per-step renorm by lane-0 (proven round-1 math)
            float r  = rlf(e, 0);
            float rr = __builtin_amdgcn_rcpf(r);
            s  = e * rr;
            M += __logf(r);
        }
    }

    // ---- epilogue ----
    float ssum = (lane < K_ST) ? sC : 0.f;
    #pragma unroll
    for (int d = 32; d >= 1; d >>= 1)
        ssum += __shfl_xor(ssum, d, 64);
    float log_norm = MC + __logf(ssum);

    if (lane == 0)
        out[b] = (L <= 0) ? 0.f : (ub - log_norm);
}

extern "C" void kernel_launch(void* const* d_in, const int* in_sizes, int n_in,
                              void* d_out, int out_size, void* d_ws, size_t ws_size,
                              hipStream_t stream) {
    const float* logits  = (const float*)d_in[0];   // [256, 2048, 48]
    const float* trans   = (const float*)d_in[1];   // [48, 48]
    const int*   targets = (const int*)  d_in[2];   // [256, 2048]
    const int*   lens    = (const int*)  d_in[3];   // [256]
    float*       out     = (float*)d_out;           // [256]

    const int B = in_sizes[3];
    crf_fwd_kernel<<<B, 64, 0, stream>>>(logits, trans, targets, lens, out);
}

// Round 5
// 262.914 us; speedup vs baseline: 2.3217x; 1.8397x over previous
//
#include <hip/hip_runtime.h>
#include <hip/hip_bf16.h>
#include <math.h>

#define TT   2048
#define KK   48
#define SEG  128
#define NFULL 15            // full segments: seg=0..14; seg=15 = per-batch tail
#define KP   68             // Qbuf pitch in ushorts (mod 4 == 0 -> 8B-aligned b64s)

typedef __attribute__((ext_vector_type(8))) short bf16x8;
typedef __attribute__((ext_vector_type(4))) float f32x4;
typedef __attribute__((ext_vector_type(4))) unsigned int u32x4;
typedef unsigned short ushort_t;

union FragU { u32x4 u; bf16x8 h; };

__device__ __forceinline__ float rlf(float x, int l) {
    return __uint_as_float((unsigned)__builtin_amdgcn_readlane((int)__float_as_uint(x), l));
}

// ---------------- Kernel 1: segment matrix products ----------------
// Job (b, seg): Q = prod over t in [t0,t1] of G_t = diag(eL_t) * Et^T, with
// per-step renorm r and log-scale sigma. Q chained in LDS col-major:
// Qb[n*KP + k] = Q[k][n]; padded k in [48,64) stays zero.
// MFMA: Y = Et^T (A, const regs) x Q_old (B, from LDS). A and B use the SAME
// feed bijection k = 32q + 16*(e>>2) + 4g + (e&3), so the hardware pairing
// cancels and the product is exact regardless of the true operand layout
// (operand layouts are mirror-symmetric; confirmed by m92-style refchecks).
// C/D layout (verified): col = lane&15, row = 4*(lane>>4) + reg.
__global__ __launch_bounds__(64) void crf_seg_kernel(
    const float* __restrict__ logits,   // [B, T, K]
    const float* __restrict__ trans,    // [K, K]
    const int*   __restrict__ lens,     // [B]
    ushort_t*    __restrict__ Qout,     // [B*16][48*48] bf16, row-major Q[m][n]
    float*       __restrict__ sigout)   // [B*16]
{
    const int b    = blockIdx.x;
    const int seg  = blockIdx.y;        // 0..15
    const int job  = b * 16 + seg;
    const int lane = threadIdx.x;
    const int c = lane & 15, g = lane >> 4;

    int t0, t1;
    if (seg < NFULL) { t0 = SEG * seg + 1; t1 = SEG * seg + SEG; }
    else {
        int L  = lens[b];
        int nf = (L >= 2) ? (L - 1) / SEG : 0;
        if (nf > NFULL) nf = NFULL;
        t0 = SEG * nf + 1; t1 = L - 1;   // may be empty (t1 < t0) -> Q = I
    }

    __shared__ ushort_t Qb[2][KK * KP];
    __shared__ float    eLs[2][64];

    for (int idx = lane; idx < KK * KP; idx += 64) { Qb[0][idx] = 0; Qb[1][idx] = 0; }
    __syncthreads();
    if (lane < KK) Qb[0][lane * KP + lane] = 0x3F80;   // bf16 1.0 on the diagonal
    __syncthreads();

    // Constant A fragments: A[mt][q] = Et^T tile, row r = 16mt + c,
    // elem e -> k = 32q + 16*(e>>2) + 4g + (e&3); zero for k >= 48.
    FragU A[3][2];
    #pragma unroll
    for (int mt = 0; mt < 3; ++mt) {
        const int r = 16 * mt + c;
        #pragma unroll
        for (int q = 0; q < 2; ++q) {
            #pragma unroll
            for (int ep = 0; ep < 4; ++ep) {
                float v0, v1;
                { int e = 2 * ep;     int kk = 32 * q + 16 * (e >> 2) + 4 * g + (e & 3);
                  v0 = (kk < KK) ? __expf(trans[kk * KK + r]) : 0.f; }
                { int e = 2 * ep + 1; int kk = 32 * q + 16 * (e >> 2) + 4 * g + (e & 3);
                  v1 = (kk < KK) ? __expf(trans[kk * KK + r]) : 0.f; }
                __hip_bfloat162 h2 = __float22bfloat162_rn(make_float2(v0, v1));
                A[mt][q].u[ep] = *(unsigned*)&h2;
            }
        }
    }

    const float* lg_b = logits + (size_t)b * TT * KK;
    const int jj = (lane < KK) ? lane : 0;
    float sg = 0.f;
    int p = 0;

    float lg_cur = lg_b[t0 * KK + jj];           // t0 <= 1921, always in-bounds
    for (int t = t0; t <= t1; ++t) {
        float lg_nxt = lg_b[(t + 1) * KK + jj];  // t+1 <= 2047, in-bounds
        const int par = t & 1;

        float eLj = __expf(lg_cur);
        if (lane < KK) eLs[par][lane] = eLj;
        asm volatile("s_waitcnt lgkmcnt(0)" ::: "memory");
        f32x4 eL4[3];
        #pragma unroll
        for (int mt = 0; mt < 3; ++mt)
            eL4[mt] = *(const f32x4*)&eLs[par][16 * mt + 4 * g];

        // B fragments = Q_old from Qb[p], same feed bijection as A
        FragU Bf[3][2];
        #pragma unroll
        for (int nt = 0; nt < 3; ++nt) {
            #pragma unroll
            for (int q = 0; q < 2; ++q) {
                const int base = (16 * nt + c) * KP + 32 * q + 4 * g;   // mod 4 == 0
                uint2 lo = *(const uint2*)&Qb[p][base];
                uint2 hi = *(const uint2*)&Qb[p][base + 16];
                Bf[nt][q].u[0] = lo.x; Bf[nt][q].u[1] = lo.y;
                Bf[nt][q].u[2] = hi.x; Bf[nt][q].u[3] = hi.y;
            }
        }

        f32x4 acc[3][3];
        #pragma unroll
        for (int mt = 0; mt < 3; ++mt)
            #pragma unroll
            for (int nt = 0; nt < 3; ++nt) {
                f32x4 z = {0.f, 0.f, 0.f, 0.f};
                f32x4 a1 = __builtin_amdgcn_mfma_f32_16x16x32_bf16(A[mt][0].h, Bf[nt][0].h, z,  0, 0, 0);
                acc[mt][nt] = __builtin_amdgcn_mfma_f32_16x16x32_bf16(A[mt][1].h, Bf[nt][1].h, a1, 0, 0, 0);
            }

        float r  = __uint_as_float((unsigned)__builtin_amdgcn_readfirstlane((int)__float_as_uint(acc[0][0][0])));
        float rr = __builtin_amdgcn_rcpf(r);
        sg += __logf(r);

        #pragma unroll
        for (int mt = 0; mt < 3; ++mt) {
            f32x4 es = eL4[mt] * rr;
            #pragma unroll
            for (int nt = 0; nt < 3; ++nt) {
                f32x4 v = acc[mt][nt] * es;
                __hip_bfloat162 h0 = __float22bfloat162_rn(make_float2(v[0], v[1]));
                __hip_bfloat162 h1 = __float22bfloat162_rn(make_float2(v[2], v[3]));
                uint2 w; w.x = *(unsigned*)&h0; w.y = *(unsigned*)&h1;
                *(uint2*)&Qb[p ^ 1][(16 * nt + c) * KP + 16 * mt + 4 * g] = w;
            }
        }
        p ^= 1;
        lg_cur = lg_nxt;
    }

    __syncthreads();
    // Epilogue: Qout[job][m][n] = Q[m][n] = Qb[p][n*KP + m]; lane = m.
    // Row m = 48 ushorts = 24 packed u32 = 6 uint4 stores at 8-ushort stride.
    if (lane < KK) {
        const int m = lane;
        unsigned w[24];
        #pragma unroll
        for (int np = 0; np < 24; ++np) {
            unsigned lo = Qb[p][(2 * np)     * KP + m];
            unsigned hi = Qb[p][(2 * np + 1) * KP + m];
            w[np] = (hi << 16) | lo;
        }
        ushort_t* dst = Qout + (size_t)job * (KK * KK) + m * KK;
        #pragma unroll
        for (int i4 = 0; i4 < 6; ++i4) {
            uint4 o; o.x = w[4*i4]; o.y = w[4*i4+1]; o.z = w[4*i4+2]; o.w = w[4*i4+3];
            *(uint4*)&dst[8 * i4] = o;     // FIXED: 8-ushort stride (was 16)
        }
    }
    if (lane == 0) sigout[job] = sg;
}

// ---------------- Kernel 2: per-batch combine + scores ----------------
__global__ __launch_bounds__(64) void crf_comb_kernel(
    const float* __restrict__ logits, const float* __restrict__ trans,
    const int* __restrict__ targets, const int* __restrict__ lens,
    const ushort_t* __restrict__ Qall, const float* __restrict__ sig,
    float* __restrict__ out)
{
    const int b = blockIdx.x, lane = threadIdx.x;
    const int jj = (lane < KK) ? lane : 0;
    const int L = lens[b];

    __shared__ float s_trans[KK * KK];
    for (int k = lane; k < KK * KK; k += 64) s_trans[k] = trans[k];
    __syncthreads();

    const float* lg_b = logits  + (size_t)b * TT * KK;
    const int*   tg_b = targets + (size_t)b * TT;

    float ub = 0.f;
    #pragma unroll 4
    for (int t = lane; t < TT; t += 64) {
        if (t < L) {
            int tg = tg_b[t];
            ub += lg_b[t * KK + tg];
            if (t >= 1) { int tp = tg_b[t - 1]; ub += s_trans[tp * KK + tg]; }
        }
    }
    #pragma unroll
    for (int d = 32; d >= 1; d >>= 1) ub += __shfl_xor(ub, d, 64);

    float log_norm = 0.f;
    if (L > 0) {
        float a0 = lg_b[jj];
        float M  = rlf(a0, 0);
        float s  = (lane < KK) ? __expf(a0 - M) : 0.f;
        int nf = (L >= 2) ? (L - 1) / SEG : 0;
        if (nf > NFULL) nf = NFULL;

        for (int ci = 0; ci <= nf; ++ci) {           // full segments, then tail
            const int job = b * 16 + ((ci < nf) ? ci : NFULL);
            const ushort_t* Qr = Qall + (size_t)job * (KK * KK) + jj * KK;
            unsigned rw[24];
            #pragma unroll
            for (int i4 = 0; i4 < 6; ++i4) {
                uint4 v = *(const uint4*)&Qr[8 * i4];   // FIXED: 8-ushort stride
                rw[4*i4] = v.x; rw[4*i4+1] = v.y; rw[4*i4+2] = v.z; rw[4*i4+3] = v.w;
            }
            float acc = 0.f;
            #pragma unroll
            for (int ip = 0; ip < 24; ++ip) {
                unsigned u = rw[ip];
                float q0 = __uint_as_float(u << 16);
                float q1 = __uint_as_float(u & 0xFFFF0000u);
                acc = fmaf(rlf(s, 2 * ip),     q0, acc);
                acc = fmaf(rlf(s, 2 * ip + 1), q1, acc);
            }
            float r  = rlf(acc, 0);
            float rr = __builtin_amdgcn_rcpf(r);
            s = (lane < KK) ? acc * rr : 0.f;
            M += __logf(r) + sig[job];
        }

        float ssum = (lane < KK) ? s : 0.f;
        #pragma unroll
        for (int d = 32; d >= 1; d >>= 1) ssum += __shfl_xor(ssum, d, 64);
        log_norm = M + __logf(ssum);
    }

    if (lane == 0) out[b] = (L <= 0) ? 0.f : (ub - log_norm);
}

// ---------------- Round-3 fallback (ws too small) ----------------
__global__ __launch_bounds__(64) void crf_fwd_fallback(
    const float* __restrict__ logits, const float* __restrict__ trans,
    const int* __restrict__ targets, const int* __restrict__ lens,
    float* __restrict__ out)
{
    const int b = blockIdx.x, lane = threadIdx.x;
    const int jj = (lane < KK) ? lane : 0;
    const int L = lens[b];
    __shared__ float s_trans[KK * KK];
    for (int k = lane; k < KK * KK; k += 64) s_trans[k] = trans[k];
    float et[KK];
    #pragma unroll
    for (int i = 0; i < KK; ++i) et[i] = __expf(trans[i * KK + jj]);
    __syncthreads();
    const float* lg_b = logits + (size_t)b * TT * KK;
    const int* tg_b = targets + (size_t)b * TT;
    float ub = 0.f;
    for (int t = lane; t < TT; t += 64) {
        if (t < L) {
            int tg = tg_b[t];
            ub += lg_b[t * KK + tg];
            if (t >= 1) { int tp = tg_b[t - 1]; ub += s_trans[tp * KK + tg]; }
        }
    }
    #pragma unroll
    for (int d = 32; d >= 1; d >>= 1) ub += __shfl_xor(ub, d, 64);
    float a0 = lg_b[jj];
    float M = rlf(a0, 0);
    float s = (lane < KK) ? __expf(a0 - M) : 0.f;
    float sC = s, MC = M;
    const int Lm1 = L - 1;
    float pf[8];
    #pragma unroll
    for (int u = 0; u < 8; ++u) pf[u] = lg_b[(1 + u) * KK + jj];
    #pragma unroll 1
    for (int cc = 0; cc < 256; ++cc) {
        #pragma unroll
        for (int u = 0; u < 8; ++u) {
            const int t = 1 + cc * 8 + u;
            float lg = pf[u];
            int nrow = t + 8; if (nrow > TT - 1) nrow = TT - 1;
            pf[u] = lg_b[nrow * KK + jj];
            float eL = __expf(lg);
            float ac0 = 0.f, ac1 = 0.f, ac2 = 0.f, ac3 = 0.f;
            #pragma unroll
            for (int i = 0; i < KK; i += 4) {
                float s0 = rlf(s, i), s1 = rlf(s, i+1), s2 = rlf(s, i+2), s3 = rlf(s, i+3);
                ac0 = fmaf(s0, et[i], ac0);   ac1 = fmaf(s1, et[i+1], ac1);
                ac2 = fmaf(s2, et[i+2], ac2); ac3 = fmaf(s3, et[i+3], ac3);
            }
            float e = ((ac0 + ac1) + (ac2 + ac3)) * eL;
            bool cap = (t == Lm1);
            sC = cap ? e : sC;  MC = cap ? M : MC;
            float r = rlf(e, 0);
            s = e * __builtin_amdgcn_rcpf(r);
            M += __logf(r);
        }
    }
    float ssum = (lane < KK) ? sC : 0.f;
    #pragma unroll
    for (int d = 32; d >= 1; d >>= 1) ssum += __shfl_xor(ssum, d, 64);
    float log_norm = MC + __logf(ssum);
    if (lane == 0) out[b] = (L <= 0) ? 0.f : (ub - log_norm);
}

extern "C" void kernel_launch(void* const* d_in, const int* in_sizes, int n_in,
                              void* d_out, int out_size, void* d_ws, size_t ws_size,
                              hipStream_t stream) {
    const float* logits  = (const float*)d_in[0];
    const float* trans   = (const float*)d_in[1];
    const int*   targets = (const int*)  d_in[2];
    const int*   lens    = (const int*)  d_in[3];
    float*       out     = (float*)d_out;
    const int B = in_sizes[3];

    const size_t qbytes = (size_t)B * 16 * KK * KK * sizeof(ushort_t);
    const size_t need   = qbytes + (size_t)B * 16 * sizeof(float);
    if (ws_size >= need) {
        ushort_t* Qout = (ushort_t*)d_ws;
        float*    sig  = (float*)((char*)d_ws + qbytes);
        crf_seg_kernel<<<dim3(B, 16), 64, 0, stream>>>(logits, trans, lens, Qout, sig);
        crf_comb_kernel<<<B, 64, 0, stream>>>(logits, trans, targets, lens, Qout, sig, out);
    } else {
        crf_fwd_fallback<<<B, 64, 0, stream>>>(logits, trans, targets, lens, out);
    }
}

// Round 6
// 246.703 us; speedup vs baseline: 2.4743x; 1.0657x over previous
//
#include <hip/hip_runtime.h>
#include <hip/hip_bf16.h>
#include <math.h>

#define TT   2048
#define KK   48
#define SEG  128
#define NFULL 15            // full segments: seg=0..14; seg=15 = per-batch tail
#define KP   68             // epilogue staging pitch in ushorts

typedef __attribute__((ext_vector_type(8))) short bf16x8;
typedef __attribute__((ext_vector_type(4))) float f32x4;
typedef __attribute__((ext_vector_type(4))) unsigned int u32x4;
typedef unsigned short ushort_t;

union FragU { u32x4 u; bf16x8 h; };

__device__ __forceinline__ float rlf(float x, int l) {
    return __uint_as_float((unsigned)__builtin_amdgcn_readlane((int)__float_as_uint(x), l));
}
__device__ __forceinline__ unsigned pk2(float a, float b) {
    __hip_bfloat162 h = __float22bfloat162_rn(make_float2(a, b));
    return *(unsigned*)&h;
}

// ---------------- Kernel 1: segment matrix products (register-resident Q) ----
// Job (b, seg): Q = prod_{t in [t0,t1]} diag(eL_t)*Et^T, renormalized each step
// by r = Y[0][0]; sigma accumulates log r. Feed bijection for A and B:
// k = 32q + 16*(e>>2) + 4g + (e&3)  (bijection-cancel: same for both operands).
// C/D layout (verified): col = lane&15, row = 16*mt + 4*(lane>>4) + reg.
// KEY: C of lane (c,g) holds exactly the k-set {4g+r, 16+4g+r, 32+4g+r} at
// n = 16nt+c that the SAME lane's next-step B fragment needs -> Q chains in
// registers, no LDS round-trip. Only eL (48 floats/step) goes through LDS,
// double-buffered one step ahead.
__global__ __launch_bounds__(64) void crf_seg_kernel(
    const float* __restrict__ logits,   // [B, T, K]
    const float* __restrict__ trans,    // [K, K]
    const int*   __restrict__ lens,     // [B]
    ushort_t*    __restrict__ Qout,     // [B*16][48*48] bf16, row-major Q[m][n]
    float*       __restrict__ sigout)   // [B*16]
{
    const int b    = blockIdx.x;
    const int seg  = blockIdx.y;        // 0..15
    const int job  = b * 16 + seg;
    const int lane = threadIdx.x;
    const int c = lane & 15, g = lane >> 4;

    int t0, t1;
    if (seg < NFULL) { t0 = SEG * seg + 1; t1 = SEG * seg + SEG; }
    else {
        int L  = lens[b];
        int nf = (L >= 2) ? (L - 1) / SEG : 0;
        if (nf > NFULL) nf = NFULL;
        t0 = SEG * nf + 1; t1 = L - 1;   // may be empty (t1 < t0) -> Q = I
    }

    __shared__ float    eLs[2][64];
    __shared__ ushort_t Qst[KK * KP];    // epilogue staging only

    // Constant A fragments: A[mt][q], row r = 16mt + c, k per bijection.
    FragU A[3][2];
    #pragma unroll
    for (int mt = 0; mt < 3; ++mt) {
        const int r = 16 * mt + c;
        #pragma unroll
        for (int q = 0; q < 2; ++q) {
            #pragma unroll
            for (int ep = 0; ep < 4; ++ep) {
                float v0, v1;
                { int e = 2 * ep;     int kk = 32 * q + 16 * (e >> 2) + 4 * g + (e & 3);
                  v0 = (kk < KK) ? __expf(trans[kk * KK + r]) : 0.f; }
                { int e = 2 * ep + 1; int kk = 32 * q + 16 * (e >> 2) + 4 * g + (e & 3);
                  v1 = (kk < KK) ? __expf(trans[kk * KK + r]) : 0.f; }
                A[mt][q].u[ep] = pk2(v0, v1);
            }
        }
    }

    // Bf init = identity columns: elem (q,e) of tile nt = I[k][16nt+c].
    FragU Bf[3][2];
    #pragma unroll
    for (int nt = 0; nt < 3; ++nt) {
        const int n = 16 * nt + c;
        #pragma unroll
        for (int q = 0; q < 2; ++q) {
            #pragma unroll
            for (int ep = 0; ep < 4; ++ep) {
                int e0 = 2 * ep, e1 = 2 * ep + 1;
                int k0 = 32 * q + 16 * (e0 >> 2) + 4 * g + (e0 & 3);
                int k1 = 32 * q + 16 * (e1 >> 2) + 4 * g + (e1 & 3);
                unsigned lo = (k0 == n) ? 0x3F80u : 0u;
                unsigned hi = (k1 == n) ? 0x3F80u : 0u;
                Bf[nt][q].u[ep] = (hi << 16) | lo;
            }
        }
    }

    const float* lg_b = logits + (size_t)b * TT * KK;
    const int jj = (lane < KK) ? lane : 0;
    float sg = 0.f;

    // Prologue: eL for t0 into buffer 0; prefetch t0+1.
    float lg_nxt = lg_b[(t0 + 1) * KK + jj];          // t0+1 <= 1922, in-bounds
    if (lane < KK) eLs[0][lane] = __expf(lg_b[t0 * KK + jj]);
    int par = 0;

    #pragma unroll 1
    for (int t = t0; t <= t1; ++t) {
        // eL for this step (written 1 iteration ago -> latency hidden)
        f32x4 eL4[3];
        #pragma unroll
        for (int mt = 0; mt < 3; ++mt)
            eL4[mt] = *(const f32x4*)&eLs[par][16 * mt + 4 * g];

        // off-chain: eL for t+1 into other buffer; prefetch t+2
        int nrow = t + 2; if (nrow > TT - 1) nrow = TT - 1;
        float lg_pf = lg_b[nrow * KK + jj];
        if (lane < KK) eLs[par ^ 1][lane] = __expf(lg_nxt);

        // Y = Et^T x Q_prev
        f32x4 acc[3][3];
        #pragma unroll
        for (int mt = 0; mt < 3; ++mt)
            #pragma unroll
            for (int nt = 0; nt < 3; ++nt) {
                f32x4 z = {0.f, 0.f, 0.f, 0.f};
                f32x4 a1 = __builtin_amdgcn_mfma_f32_16x16x32_bf16(A[mt][0].h, Bf[nt][0].h, z,  0, 0, 0);
                acc[mt][nt] = __builtin_amdgcn_mfma_f32_16x16x32_bf16(A[mt][1].h, Bf[nt][1].h, a1, 0, 0, 0);
            }

        float r  = __uint_as_float((unsigned)__builtin_amdgcn_readfirstlane((int)__float_as_uint(acc[0][0][0])));
        float rr = __builtin_amdgcn_rcpf(r);
        sg += __logf(r);

        // Row-scale by eL*rr, repack directly into next step's B fragments.
        f32x4 es0 = eL4[0] * rr, es1 = eL4[1] * rr, es2 = eL4[2] * rr;
        #pragma unroll
        for (int nt = 0; nt < 3; ++nt) {
            f32x4 v0 = acc[0][nt] * es0;     // k = 4g + r
            f32x4 v1 = acc[1][nt] * es1;     // k = 16 + 4g + r
            f32x4 v2 = acc[2][nt] * es2;     // k = 32 + 4g + r
            Bf[nt][0].u[0] = pk2(v0[0], v0[1]);
            Bf[nt][0].u[1] = pk2(v0[2], v0[3]);
            Bf[nt][0].u[2] = pk2(v1[0], v1[1]);
            Bf[nt][0].u[3] = pk2(v1[2], v1[3]);
            Bf[nt][1].u[0] = pk2(v2[0], v2[1]);
            Bf[nt][1].u[1] = pk2(v2[2], v2[3]);
            Bf[nt][1].u[2] = 0u;
            Bf[nt][1].u[3] = 0u;
        }

        lg_nxt = lg_pf;
        par ^= 1;
    }

    // ---- epilogue: stage Bf (= final Q, bf16) to LDS, then linear store ----
    #pragma unroll
    for (int nt = 0; nt < 3; ++nt) {
        ushort_t* basep = &Qst[(16 * nt + c) * KP];
        *(unsigned*)&basep[4 * g]          = Bf[nt][0].u[0];
        *(unsigned*)&basep[4 * g + 2]      = Bf[nt][0].u[1];
        *(unsigned*)&basep[16 + 4 * g]     = Bf[nt][0].u[2];
        *(unsigned*)&basep[16 + 4 * g + 2] = Bf[nt][0].u[3];
        *(unsigned*)&basep[32 + 4 * g]     = Bf[nt][1].u[0];
        *(unsigned*)&basep[32 + 4 * g + 2] = Bf[nt][1].u[1];
    }
    __syncthreads();

    // Qout[job][m][n] = Q[m][n] = Qst[n*KP + m]; lane = m.
    if (lane < KK) {
        const int m = lane;
        unsigned w[24];
        #pragma unroll
        for (int np = 0; np < 24; ++np) {
            unsigned lo = Qst[(2 * np)     * KP + m];
            unsigned hi = Qst[(2 * np + 1) * KP + m];
            w[np] = (hi << 16) | lo;
        }
        ushort_t* dst = Qout + (size_t)job * (KK * KK) + m * KK;
        #pragma unroll
        for (int i4 = 0; i4 < 6; ++i4) {
            uint4 o; o.x = w[4*i4]; o.y = w[4*i4+1]; o.z = w[4*i4+2]; o.w = w[4*i4+3];
            *(uint4*)&dst[8 * i4] = o;
        }
    }
    if (lane == 0) sigout[job] = sg;
}

// ---------------- Kernel 2: per-batch combine + scores (proven round-5) ----
__global__ __launch_bounds__(64) void crf_comb_kernel(
    const float* __restrict__ logits, const float* __restrict__ trans,
    const int* __restrict__ targets, const int* __restrict__ lens,
    const ushort_t* __restrict__ Qall, const float* __restrict__ sig,
    float* __restrict__ out)
{
    const int b = blockIdx.x, lane = threadIdx.x;
    const int jj = (lane < KK) ? lane : 0;
    const int L = lens[b];

    __shared__ float s_trans[KK * KK];
    for (int k = lane; k < KK * KK; k += 64) s_trans[k] = trans[k];
    __syncthreads();

    const float* lg_b = logits  + (size_t)b * TT * KK;
    const int*   tg_b = targets + (size_t)b * TT;

    float ub = 0.f;
    #pragma unroll 4
    for (int t = lane; t < TT; t += 64) {
        if (t < L) {
            int tg = tg_b[t];
            ub += lg_b[t * KK + tg];
            if (t >= 1) { int tp = tg_b[t - 1]; ub += s_trans[tp * KK + tg]; }
        }
    }
    #pragma unroll
    for (int d = 32; d >= 1; d >>= 1) ub += __shfl_xor(ub, d, 64);

    float log_norm = 0.f;
    if (L > 0) {
        float a0 = lg_b[jj];
        float M  = rlf(a0, 0);
        float s  = (lane < KK) ? __expf(a0 - M) : 0.f;
        int nf = (L >= 2) ? (L - 1) / SEG : 0;
        if (nf > NFULL) nf = NFULL;

        for (int ci = 0; ci <= nf; ++ci) {           // full segments, then tail
            const int job = b * 16 + ((ci < nf) ? ci : NFULL);
            const ushort_t* Qr = Qall + (size_t)job * (KK * KK) + jj * KK;
            unsigned rw[24];
            #pragma unroll
            for (int i4 = 0; i4 < 6; ++i4) {
                uint4 v = *(const uint4*)&Qr[8 * i4];
                rw[4*i4] = v.x; rw[4*i4+1] = v.y; rw[4*i4+2] = v.z; rw[4*i4+3] = v.w;
            }
            float acc = 0.f;
            #pragma unroll
            for (int ip = 0; ip < 24; ++ip) {
                unsigned u = rw[ip];
                float q0 = __uint_as_float(u << 16);
                float q1 = __uint_as_float(u & 0xFFFF0000u);
                acc = fmaf(rlf(s, 2 * ip),     q0, acc);
                acc = fmaf(rlf(s, 2 * ip + 1), q1, acc);
            }
            float r  = rlf(acc, 0);
            float rr = __builtin_amdgcn_rcpf(r);
            s = (lane < KK) ? acc * rr : 0.f;
            M += __logf(r) + sig[job];
        }

        float ssum = (lane < KK) ? s : 0.f;
        #pragma unroll
        for (int d = 32; d >= 1; d >>= 1) ssum += __shfl_xor(ssum, d, 64);
        log_norm = M + __logf(ssum);
    }

    if (lane == 0) out[b] = (L <= 0) ? 0.f : (ub - log_norm);
}

// ---------------- Round-3 fallback (ws too small) ----------------
__global__ __launch_bounds__(64) void crf_fwd_fallback(
    const float* __restrict__ logits, const float* __restrict__ trans,
    const int* __restrict__ targets, const int* __restrict__ lens,
    float* __restrict__ out)
{
    const int b = blockIdx.x, lane = threadIdx.x;
    const int jj = (lane < KK) ? lane : 0;
    const int L = lens[b];
    __shared__ float s_trans[KK * KK];
    for (int k = lane; k < KK * KK; k += 64) s_trans[k] = trans[k];
    float et[KK];
    #pragma unroll
    for (int i = 0; i < KK; ++i) et[i] = __expf(trans[i * KK + jj]);
    __syncthreads();
    const float* lg_b = logits + (size_t)b * TT * KK;
    const int* tg_b = targets + (size_t)b * TT;
    float ub = 0.f;
    for (int t = lane; t < TT; t += 64) {
        if (t < L) {
            int tg = tg_b[t];
            ub += lg_b[t * KK + tg];
            if (t >= 1) { int tp = tg_b[t - 1]; ub += s_trans[tp * KK + tg]; }
        }
    }
    #pragma unroll
    for (int d = 32; d >= 1; d >>= 1) ub += __shfl_xor(ub, d, 64);
    float a0 = lg_b[jj];
    float M = rlf(a0, 0);
    float s = (lane < KK) ? __expf(a0 - M) : 0.f;
    float sC = s, MC = M;
    const int Lm1 = L - 1;
    float pf[8];
    #pragma unroll
    for (int u = 0; u < 8; ++u) pf[u] = lg_b[(1 + u) * KK + jj];
    #pragma unroll 1
    for (int cc = 0; cc < 256; ++cc) {
        #pragma unroll
        for (int u = 0; u < 8; ++u) {
            const int t = 1 + cc * 8 + u;
            float lg = pf[u];
            int nrow = t + 8; if (nrow > TT - 1) nrow = TT - 1;
            pf[u] = lg_b[nrow * KK + jj];
            float eL = __expf(lg);
            float ac0 = 0.f, ac1 = 0.f, ac2 = 0.f, ac3 = 0.f;
            #pragma unroll
            for (int i = 0; i < KK; i += 4) {
                float s0 = rlf(s, i), s1 = rlf(s, i+1), s2 = rlf(s, i+2), s3 = rlf(s, i+3);
                ac0 = fmaf(s0, et[i], ac0);   ac1 = fmaf(s1, et[i+1], ac1);
                ac2 = fmaf(s2, et[i+2], ac2); ac3 = fmaf(s3, et[i+3], ac3);
            }
            float e = ((ac0 + ac1) + (ac2 + ac3)) * eL;
            bool cap = (t == Lm1);
            sC = cap ? e : sC;  MC = cap ? M : MC;
            float r = rlf(e, 0);
            s = e * __builtin_amdgcn_rcpf(r);
            M += __logf(r);
        }
    }
    float ssum = (lane < KK) ? sC : 0.f;
    #pragma unroll
    for (int d = 32; d >= 1; d >>= 1) ssum += __shfl_xor(ssum, d, 64);
    float log_norm = MC + __logf(ssum);
    if (lane == 0) out[b] = (L <= 0) ? 0.f : (ub - log_norm);
}

extern "C" void kernel_launch(void* const* d_in, const int* in_sizes, int n_in,
                              void* d_out, int out_size, void* d_ws, size_t ws_size,
                              hipStream_t stream) {
    const float* logits  = (const float*)d_in[0];
    const float* trans   = (const float*)d_in[1];
    const int*   targets = (const int*)  d_in[2];
    const int*   lens    = (const int*)  d_in[3];
    float*       out     = (float*)d_out;
    const int B = in_sizes[3];

    const size_t qbytes = (size_t)B * 16 * KK * KK * sizeof(ushort_t);
    const size_t need   = qbytes + (size_t)B * 16 * sizeof(float);
    if (ws_size >= need) {
        ushort_t* Qout = (ushort_t*)d_ws;
        float*    sig  = (float*)((char*)d_ws + qbytes);
        crf_seg_kernel<<<dim3(B, 16), 64, 0, stream>>>(logits, trans, lens, Qout, sig);
        crf_comb_kernel<<<B, 64, 0, stream>>>(logits, trans, targets, lens, Qout, sig, out);
    } else {
        crf_fwd_fallback<<<B, 64, 0, stream>>>(logits, trans, targets, lens, out);
    }
}

// Round 7
// 202.498 us; speedup vs baseline: 3.0144x; 1.2183x over previous
//
#include <hip/hip_runtime.h>
#include <hip/hip_bf16.h>
#include <math.h>

#define TT   2048
#define KK   48
#define SEG  128
#define NFULL 15            // full segments: seg=0..14; seg=15 = per-batch tail
#define KP   68             // epilogue staging pitch in ushorts

typedef __attribute__((ext_vector_type(8))) short bf16x8;
typedef __attribute__((ext_vector_type(4))) float f32x4;
typedef __attribute__((ext_vector_type(4))) unsigned int u32x4;
typedef unsigned short ushort_t;

union FragU { u32x4 u; bf16x8 h; };

__device__ __forceinline__ float rlf(float x, int l) {
    return __uint_as_float((unsigned)__builtin_amdgcn_readlane((int)__float_as_uint(x), l));
}
// software pack (setup/epilogue only — full RNE + NaN handling, runs once)
__device__ __forceinline__ unsigned pk2(float a, float b) {
    __hip_bfloat162 h = __float22bfloat162_rn(make_float2(a, b));
    return *(unsigned*)&h;
}
// HW pack for the hot loop: single v_cvt_pk_bf16_f32 (RNE; gfx950-verified)
__device__ __forceinline__ unsigned pk2a(float a, float b) {
    unsigned r;
    asm("v_cvt_pk_bf16_f32 %0, %1, %2" : "=v"(r) : "v"(a), "v"(b));
    return r;
}

// ---------------- Kernel 1: segment matrix products (register-resident Q) ----
// Job (b, seg): Q = prod_{t in [t0,t1]} diag(eL_t)*Et^T, renormalized each step
// by r = Y[0][0]; sigma accumulates log r. Feed bijection for A and B:
// k = 32q + 16*(e>>2) + 4g + (e&3)  (bijection-cancel: same for both operands).
// C/D layout (verified): col = lane&15, row = 16*mt + 4*(lane>>4) + reg.
// C of lane (c,g) holds exactly the k-set the SAME lane's next-step B fragment
// needs -> Q chains in registers, no LDS round-trip. Only eL (48 floats/step)
// goes through LDS, double-buffered one step ahead.
__global__ __launch_bounds__(64) void crf_seg_kernel(
    const float* __restrict__ logits,   // [B, T, K]
    const float* __restrict__ trans,    // [K, K]
    const int*   __restrict__ lens,     // [B]
    ushort_t*    __restrict__ Qout,     // [B*16][48*48] bf16, row-major Q[m][n]
    float*       __restrict__ sigout)   // [B*16]
{
    const int b    = blockIdx.x;
    const int seg  = blockIdx.y;        // 0..15
    const int job  = b * 16 + seg;
    const int lane = threadIdx.x;
    const int c = lane & 15, g = lane >> 4;

    int t0, t1;
    if (seg < NFULL) { t0 = SEG * seg + 1; t1 = SEG * seg + SEG; }
    else {
        int L  = lens[b];
        int nf = (L >= 2) ? (L - 1) / SEG : 0;
        if (nf > NFULL) nf = NFULL;
        t0 = SEG * nf + 1; t1 = L - 1;   // may be empty (t1 < t0) -> Q = I
    }

    __shared__ float    eLs[2][64];
    __shared__ ushort_t Qst[KK * KP];    // epilogue staging only

    // Constant A fragments: A[mt][q], row r = 16mt + c, k per bijection.
    FragU A[3][2];
    #pragma unroll
    for (int mt = 0; mt < 3; ++mt) {
        const int r = 16 * mt + c;
        #pragma unroll
        for (int q = 0; q < 2; ++q) {
            #pragma unroll
            for (int ep = 0; ep < 4; ++ep) {
                float v0, v1;
                { int e = 2 * ep;     int kk = 32 * q + 16 * (e >> 2) + 4 * g + (e & 3);
                  v0 = (kk < KK) ? __expf(trans[kk * KK + r]) : 0.f; }
                { int e = 2 * ep + 1; int kk = 32 * q + 16 * (e >> 2) + 4 * g + (e & 3);
                  v1 = (kk < KK) ? __expf(trans[kk * KK + r]) : 0.f; }
                A[mt][q].u[ep] = pk2(v0, v1);
            }
        }
    }

    // Bf init = identity columns: elem (q,e) of tile nt = I[k][16nt+c].
    FragU Bf[3][2];
    #pragma unroll
    for (int nt = 0; nt < 3; ++nt) {
        const int n = 16 * nt + c;
        #pragma unroll
        for (int q = 0; q < 2; ++q) {
            #pragma unroll
            for (int ep = 0; ep < 4; ++ep) {
                int e0 = 2 * ep, e1 = 2 * ep + 1;
                int k0 = 32 * q + 16 * (e0 >> 2) + 4 * g + (e0 & 3);
                int k1 = 32 * q + 16 * (e1 >> 2) + 4 * g + (e1 & 3);
                unsigned lo = (k0 == n) ? 0x3F80u : 0u;
                unsigned hi = (k1 == n) ? 0x3F80u : 0u;
                Bf[nt][q].u[ep] = (hi << 16) | lo;
            }
        }
    }

    const float* lg_b = logits + (size_t)b * TT * KK;
    const int jj = (lane < KK) ? lane : 0;
    float sg = 0.f;

    // Prologue: eL for t0 into buffer 0; prefetch t0+1.
    float lg_nxt = lg_b[(t0 + 1) * KK + jj];          // t0+1 <= 1922, in-bounds
    if (lane < KK) eLs[0][lane] = __expf(lg_b[t0 * KK + jj]);
    int par = 0;

    #pragma unroll 1
    for (int t = t0; t <= t1; ++t) {
        // eL for this step (written 1 iteration ago -> latency hidden)
        f32x4 eL4[3];
        #pragma unroll
        for (int mt = 0; mt < 3; ++mt)
            eL4[mt] = *(const f32x4*)&eLs[par][16 * mt + 4 * g];

        // off-chain: eL for t+1 into other buffer; prefetch t+2
        int nrow = t + 2; if (nrow > TT - 1) nrow = TT - 1;
        float lg_pf = lg_b[nrow * KK + jj];
        if (lane < KK) eLs[par ^ 1][lane] = __expf(lg_nxt);

        // Y = Et^T x Q_prev
        f32x4 acc[3][3];
        #pragma unroll
        for (int mt = 0; mt < 3; ++mt)
            #pragma unroll
            for (int nt = 0; nt < 3; ++nt) {
                f32x4 z = {0.f, 0.f, 0.f, 0.f};
                f32x4 a1 = __builtin_amdgcn_mfma_f32_16x16x32_bf16(A[mt][0].h, Bf[nt][0].h, z,  0, 0, 0);
                acc[mt][nt] = __builtin_amdgcn_mfma_f32_16x16x32_bf16(A[mt][1].h, Bf[nt][1].h, a1, 0, 0, 0);
            }

        float r  = __uint_as_float((unsigned)__builtin_amdgcn_readfirstlane((int)__float_as_uint(acc[0][0][0])));
        float rr = __builtin_amdgcn_rcpf(r);
        sg += __logf(r);

        // Row-scale by eL*rr, repack directly into next step's B fragments.
        // HW v_cvt_pk_bf16_f32 (1 instr/pair) — was software RNE (~7 instr/val).
        f32x4 es0 = eL4[0] * rr, es1 = eL4[1] * rr, es2 = eL4[2] * rr;
        #pragma unroll
        for (int nt = 0; nt < 3; ++nt) {
            f32x4 v0 = acc[0][nt] * es0;     // k = 4g + r
            f32x4 v1 = acc[1][nt] * es1;     // k = 16 + 4g + r
            f32x4 v2 = acc[2][nt] * es2;     // k = 32 + 4g + r
            Bf[nt][0].u[0] = pk2a(v0[0], v0[1]);
            Bf[nt][0].u[1] = pk2a(v0[2], v0[3]);
            Bf[nt][0].u[2] = pk2a(v1[0], v1[1]);
            Bf[nt][0].u[3] = pk2a(v1[2], v1[3]);
            Bf[nt][1].u[0] = pk2a(v2[0], v2[1]);
            Bf[nt][1].u[1] = pk2a(v2[2], v2[3]);
            Bf[nt][1].u[2] = 0u;
            Bf[nt][1].u[3] = 0u;
        }

        lg_nxt = lg_pf;
        par ^= 1;
    }

    // ---- epilogue: stage Bf (= final Q, bf16) to LDS, then linear store ----
    #pragma unroll
    for (int nt = 0; nt < 3; ++nt) {
        ushort_t* basep = &Qst[(16 * nt + c) * KP];
        *(unsigned*)&basep[4 * g]          = Bf[nt][0].u[0];
        *(unsigned*)&basep[4 * g + 2]      = Bf[nt][0].u[1];
        *(unsigned*)&basep[16 + 4 * g]     = Bf[nt][0].u[2];
        *(unsigned*)&basep[16 + 4 * g + 2] = Bf[nt][0].u[3];
        *(unsigned*)&basep[32 + 4 * g]     = Bf[nt][1].u[0];
        *(unsigned*)&basep[32 + 4 * g + 2] = Bf[nt][1].u[1];
    }
    __syncthreads();

    // Qout[job][m][n] = Q[m][n] = Qst[n*KP + m]; lane = m.
    if (lane < KK) {
        const int m = lane;
        unsigned w[24];
        #pragma unroll
        for (int np = 0; np < 24; ++np) {
            unsigned lo = Qst[(2 * np)     * KP + m];
            unsigned hi = Qst[(2 * np + 1) * KP + m];
            w[np] = (hi << 16) | lo;
        }
        ushort_t* dst = Qout + (size_t)job * (KK * KK) + m * KK;
        #pragma unroll
        for (int i4 = 0; i4 < 6; ++i4) {
            uint4 o; o.x = w[4*i4]; o.y = w[4*i4+1]; o.z = w[4*i4+2]; o.w = w[4*i4+3];
            *(uint4*)&dst[8 * i4] = o;
        }
    }
    if (lane == 0) sigout[job] = sg;
}

// ---------------- Kernel 2: per-batch combine + scores (proven round-5) ----
__global__ __launch_bounds__(64) void crf_comb_kernel(
    const float* __restrict__ logits, const float* __restrict__ trans,
    const int* __restrict__ targets, const int* __restrict__ lens,
    const ushort_t* __restrict__ Qall, const float* __restrict__ sig,
    float* __restrict__ out)
{
    const int b = blockIdx.x, lane = threadIdx.x;
    const int jj = (lane < KK) ? lane : 0;
    const int L = lens[b];

    __shared__ float s_trans[KK * KK];
    for (int k = lane; k < KK * KK; k += 64) s_trans[k] = trans[k];
    __syncthreads();

    const float* lg_b = logits  + (size_t)b * TT * KK;
    const int*   tg_b = targets + (size_t)b * TT;

    float ub = 0.f;
    #pragma unroll 4
    for (int t = lane; t < TT; t += 64) {
        if (t < L) {
            int tg = tg_b[t];
            ub += lg_b[t * KK + tg];
            if (t >= 1) { int tp = tg_b[t - 1]; ub += s_trans[tp * KK + tg]; }
        }
    }
    #pragma unroll
    for (int d = 32; d >= 1; d >>= 1) ub += __shfl_xor(ub, d, 64);

    float log_norm = 0.f;
    if (L > 0) {
        float a0 = lg_b[jj];
        float M  = rlf(a0, 0);
        float s  = (lane < KK) ? __expf(a0 - M) : 0.f;
        int nf = (L >= 2) ? (L - 1) / SEG : 0;
        if (nf > NFULL) nf = NFULL;

        for (int ci = 0; ci <= nf; ++ci) {           // full segments, then tail
            const int job = b * 16 + ((ci < nf) ? ci : NFULL);
            const ushort_t* Qr = Qall + (size_t)job * (KK * KK) + jj * KK;
            unsigned rw[24];
            #pragma unroll
            for (int i4 = 0; i4 < 6; ++i4) {
                uint4 v = *(const uint4*)&Qr[8 * i4];
                rw[4*i4] = v.x; rw[4*i4+1] = v.y; rw[4*i4+2] = v.z; rw[4*i4+3] = v.w;
            }
            float acc = 0.f;
            #pragma unroll
            for (int ip = 0; ip < 24; ++ip) {
                unsigned u = rw[ip];
                float q0 = __uint_as_float(u << 16);
                float q1 = __uint_as_float(u & 0xFFFF0000u);
                acc = fmaf(rlf(s, 2 * ip),     q0, acc);
                acc = fmaf(rlf(s, 2 * ip + 1), q1, acc);
            }
            float r  = rlf(acc, 0);
            float rr = __builtin_amdgcn_rcpf(r);
            s = (lane < KK) ? acc * rr : 0.f;
            M += __logf(r) + sig[job];
        }

        float ssum = (lane < KK) ? s : 0.f;
        #pragma unroll
        for (int d = 32; d >= 1; d >>= 1) ssum += __shfl_xor(ssum, d, 64);
        log_norm = M + __logf(ssum);
    }

    if (lane == 0) out[b] = (L <= 0) ? 0.f : (ub - log_norm);
}

// ---------------- Round-3 fallback (ws too small) ----------------
__global__ __launch_bounds__(64) void crf_fwd_fallback(
    const float* __restrict__ logits, const float* __restrict__ trans,
    const int* __restrict__ targets, const int* __restrict__ lens,
    float* __restrict__ out)
{
    const int b = blockIdx.x, lane = threadIdx.x;
    const int jj = (lane < KK) ? lane : 0;
    const int L = lens[b];
    __shared__ float s_trans[KK * KK];
    for (int k = lane; k < KK * KK; k += 64) s_trans[k] = trans[k];
    float et[KK];
    #pragma unroll
    for (int i = 0; i < KK; ++i) et[i] = __expf(trans[i * KK + jj]);
    __syncthreads();
    const float* lg_b = logits + (size_t)b * TT * KK;
    const int* tg_b = targets + (size_t)b * TT;
    float ub = 0.f;
    for (int t = lane; t < TT; t += 64) {
        if (t < L) {
            int tg = tg_b[t];
            ub += lg_b[t * KK + tg];
            if (t >= 1) { int tp = tg_b[t - 1]; ub += s_trans[tp * KK + tg]; }
        }
    }
    #pragma unroll
    for (int d = 32; d >= 1; d >>= 1) ub += __shfl_xor(ub, d, 64);
    float a0 = lg_b[jj];
    float M = rlf(a0, 0);
    float s = (lane < KK) ? __expf(a0 - M) : 0.f;
    float sC = s, MC = M;
    const int Lm1 = L - 1;
    float pf[8];
    #pragma unroll
    for (int u = 0; u < 8; ++u) pf[u] = lg_b[(1 + u) * KK + jj];
    #pragma unroll 1
    for (int cc = 0; cc < 256; ++cc) {
        #pragma unroll
        for (int u = 0; u < 8; ++u) {
            const int t = 1 + cc * 8 + u;
            float lg = pf[u];
            int nrow = t + 8; if (nrow > TT - 1) nrow = TT - 1;
            pf[u] = lg_b[nrow * KK + jj];
            float eL = __expf(lg);
            float ac0 = 0.f, ac1 = 0.f, ac2 = 0.f, ac3 = 0.f;
            #pragma unroll
            for (int i = 0; i < KK; i += 4) {
                float s0 = rlf(s, i), s1 = rlf(s, i+1), s2 = rlf(s, i+2), s3 = rlf(s, i+3);
                ac0 = fmaf(s0, et[i], ac0);   ac1 = fmaf(s1, et[i+1], ac1);
                ac2 = fmaf(s2, et[i+2], ac2); ac3 = fmaf(s3, et[i+3], ac3);
            }
            float e = ((ac0 + ac1) + (ac2 + ac3)) * eL;
            bool cap = (t == Lm1);
            sC = cap ? e : sC;  MC = cap ? M : MC;
            float r = rlf(e, 0);
            s = e * __builtin_amdgcn_rcpf(r);
            M += __logf(r);
        }
    }
    float ssum = (lane < KK) ? sC : 0.f;
    #pragma unroll
    for (int d = 32; d >= 1; d >>= 1) ssum += __shfl_xor(ssum, d, 64);
    float log_norm = MC + __logf(ssum);
    if (lane == 0) out[b] = (L <= 0) ? 0.f : (ub - log_norm);
}

extern "C" void kernel_launch(void* const* d_in, const int* in_sizes, int n_in,
                              void* d_out, int out_size, void* d_ws, size_t ws_size,
                              hipStream_t stream) {
    const float* logits  = (const float*)d_in[0];
    const float* trans   = (const float*)d_in[1];
    const int*   targets = (const int*)  d_in[2];
    const int*   lens    = (const int*)  d_in[3];
    float*       out     = (float*)d_out;
    const int B = in_sizes[3];

    const size_t qbytes = (size_t)B * 16 * KK * KK * sizeof(ushort_t);
    const size_t need   = qbytes + (size_t)B * 16 * sizeof(float);
    if (ws_size >= need) {
        ushort_t* Qout = (ushort_t*)d_ws;
        float*    sig  = (float*)((char*)d_ws + qbytes);
        crf_seg_kernel<<<dim3(B, 16), 64, 0, stream>>>(logits, trans, lens, Qout, sig);
        crf_comb_kernel<<<B, 64, 0, stream>>>(logits, trans, targets, lens, Qout, sig, out);
    } else {
        crf_fwd_fallback<<<B, 64, 0, stream>>>(logits, trans, targets, lens, out);
    }
}

// Round 8
// 199.698 us; speedup vs baseline: 3.0567x; 1.0140x over previous
//
#include <hip/hip_runtime.h>
#include <hip/hip_bf16.h>
#include <math.h>

#define TT   2048
#define KK   48
#define SEG  128
#define NFULL 15            // full segments: seg=0..14; seg=15 = per-batch tail
#define KP   68             // epilogue staging pitch in ushorts

typedef __attribute__((ext_vector_type(8))) short bf16x8;
typedef __attribute__((ext_vector_type(4))) float f32x4;
typedef __attribute__((ext_vector_type(2))) float f32x2;
typedef __attribute__((ext_vector_type(4))) unsigned int u32x4;
typedef unsigned short ushort_t;

union FragU { u32x4 u; bf16x8 h; };
union Q4   { f32x4 v; f32x2 h[2]; };

__device__ __forceinline__ float rlf(float x, int l) {
    return __uint_as_float((unsigned)__builtin_amdgcn_readlane((int)__float_as_uint(x), l));
}
// software pack (setup only)
__device__ __forceinline__ unsigned pk2(float a, float b) {
    __hip_bfloat162 h = __float22bfloat162_rn(make_float2(a, b));
    return *(unsigned*)&h;
}
// HW pack: single v_cvt_pk_bf16_f32 (RNE; gfx950-verified R7: -45us)
__device__ __forceinline__ unsigned pk2a(float a, float b) {
    unsigned r;
    asm("v_cvt_pk_bf16_f32 %0, %1, %2" : "=v"(r) : "v"(a), "v"(b));
    return r;
}
// packed fp32 mul (VOP3P, gfx90a+): d.lo=a.lo*b.lo, d.hi=a.hi*b.hi
__device__ __forceinline__ f32x2 pkmul(f32x2 a, f32x2 b) {
    f32x2 d;
    asm("v_pk_mul_f32 %0, %1, %2" : "=v"(d) : "v"(a), "v"(b));
    return d;
}

// ---------------- Kernel 1: segment matrix products (register-resident Q) ----
// Q = prod_{t in [t0,t1]} diag(eL_t)*Et^T, renormalized each step by r=Y[0][0];
// sigma accumulates log r. Feed bijection k = 32q+16(e>>2)+4g+(e&3) for BOTH
// operands (bijection-cancel). C/D: col=lane&15, row=16mt+4(lane>>4)+reg.
// Q chains in registers; eL staged via LDS dbuf one step ahead; raw logits
// ring-prefetched 8 steps deep (R3-proven latency fix).
__global__ __launch_bounds__(64) void crf_seg_kernel(
    const float* __restrict__ logits,   // [B, T, K]
    const float* __restrict__ trans,    // [K, K]
    const int*   __restrict__ lens,     // [B]
    ushort_t*    __restrict__ Qout,     // [B*16][48*48] bf16, row-major Q[m][n]
    float*       __restrict__ sigout)   // [B*16]
{
    const int b    = blockIdx.x;
    const int seg  = blockIdx.y;        // 0..15
    const int job  = b * 16 + seg;
    const int lane = threadIdx.x;
    const int c = lane & 15, g = lane >> 4;

    int t0, t1;
    if (seg < NFULL) { t0 = SEG * seg + 1; t1 = SEG * seg + SEG; }
    else {
        int L  = lens[b];
        int nf = (L >= 2) ? (L - 1) / SEG : 0;
        if (nf > NFULL) nf = NFULL;
        t0 = SEG * nf + 1; t1 = L - 1;   // may be empty (t1 < t0) -> Q = I
    }

    __shared__ float    eLs[2][64];
    __shared__ ushort_t Qst[KK * KP];    // epilogue staging only

    // Constant A fragments: A[mt][q], row r = 16mt + c, k per bijection.
    FragU A[3][2];
    #pragma unroll
    for (int mt = 0; mt < 3; ++mt) {
        const int r = 16 * mt + c;
        #pragma unroll
        for (int q = 0; q < 2; ++q) {
            #pragma unroll
            for (int ep = 0; ep < 4; ++ep) {
                float v0, v1;
                { int e = 2 * ep;     int kk = 32 * q + 16 * (e >> 2) + 4 * g + (e & 3);
                  v0 = (kk < KK) ? __expf(trans[kk * KK + r]) : 0.f; }
                { int e = 2 * ep + 1; int kk = 32 * q + 16 * (e >> 2) + 4 * g + (e & 3);
                  v1 = (kk < KK) ? __expf(trans[kk * KK + r]) : 0.f; }
                A[mt][q].u[ep] = pk2(v0, v1);
            }
        }
    }

    // Bf init = identity columns: elem (q,e) of tile nt = I[k][16nt+c].
    FragU Bf[3][2];
    #pragma unroll
    for (int nt = 0; nt < 3; ++nt) {
        const int n = 16 * nt + c;
        #pragma unroll
        for (int q = 0; q < 2; ++q) {
            #pragma unroll
            for (int ep = 0; ep < 4; ++ep) {
                int e0 = 2 * ep, e1 = 2 * ep + 1;
                int k0 = 32 * q + 16 * (e0 >> 2) + 4 * g + (e0 & 3);
                int k1 = 32 * q + 16 * (e1 >> 2) + 4 * g + (e1 & 3);
                unsigned lo = (k0 == n) ? 0x3F80u : 0u;
                unsigned hi = (k1 == n) ? 0x3F80u : 0u;
                Bf[nt][q].u[ep] = (hi << 16) | lo;
            }
        }
    }

    const float* lg_b = logits + (size_t)b * TT * KK;
    const int jj = (lane < KK) ? lane : 0;
    float sg = 0.f;
    const int nsteps = t1 - t0 + 1;

// One step. u_ = position in chunk (compile-time), G_ = junk-guard enable.
// At iter i (step t = t0+i): eLs[par] holds eL_t; pf[(u+1)&7] holds lg_{t0+i+1};
// refill pf[(u+1)&7] with row t0+i+9 (used 8 iters later).
#define STEP(u_, G_)                                                          \
    {                                                                         \
        const int i = 8 * cs + (u_);                                          \
        f32x4 eL4[3];                                                         \
        _Pragma("unroll")                                                     \
        for (int mt = 0; mt < 3; ++mt)                                        \
            eL4[mt] = *(const f32x4*)&eLs[par][16 * mt + 4 * g];              \
        float lgn = pf[((u_) + 1) & 7];                                       \
        int nr = t0 + i + 9; if (nr > TT - 1) nr = TT - 1;                    \
        pf[((u_) + 1) & 7] = lg_b[nr * KK + jj];                              \
        if (lane < KK) eLs[par ^ 1][lane] = __expf(lgn);                      \
        f32x4 acc[3][3];                                                      \
        _Pragma("unroll")                                                     \
        for (int mt = 0; mt < 3; ++mt)                                        \
            _Pragma("unroll")                                                 \
            for (int nt = 0; nt < 3; ++nt) {                                  \
                f32x4 z = {0.f, 0.f, 0.f, 0.f};                               \
                f32x4 a1 = __builtin_amdgcn_mfma_f32_16x16x32_bf16(           \
                               A[mt][0].h, Bf[nt][0].h, z, 0, 0, 0);          \
                acc[mt][nt] = __builtin_amdgcn_mfma_f32_16x16x32_bf16(        \
                               A[mt][1].h, Bf[nt][1].h, a1, 0, 0, 0);         \
            }                                                                 \
        float r = __uint_as_float((unsigned)__builtin_amdgcn_readfirstlane(   \
                      (int)__float_as_uint(acc[0][0][0])));                   \
        float rr = __builtin_amdgcn_rcpf(r);                                  \
        float logr = __logf(r);                                               \
        bool jk = G_ ? (i >= nsteps) : false;                                 \
        sg += jk ? 0.f : logr;                                                \
        f32x2 rr2 = {rr, rr};                                                 \
        Q4 es0, es1, es2;                                                     \
        { Q4 e0_; e0_.v = eL4[0]; es0.h[0] = pkmul(e0_.h[0], rr2);            \
                                  es0.h[1] = pkmul(e0_.h[1], rr2); }          \
        { Q4 e1_; e1_.v = eL4[1]; es1.h[0] = pkmul(e1_.h[0], rr2);            \
                                  es1.h[1] = pkmul(e1_.h[1], rr2); }          \
        { Q4 e2_; e2_.v = eL4[2]; es2.h[0] = pkmul(e2_.h[0], rr2);            \
                                  es2.h[1] = pkmul(e2_.h[1], rr2); }          \
        _Pragma("unroll")                                                     \
        for (int nt = 0; nt < 3; ++nt) {                                      \
            Q4 a0_, a1_, a2_;                                                 \
            a0_.v = acc[0][nt]; a1_.v = acc[1][nt]; a2_.v = acc[2][nt];       \
            f32x2 v00 = pkmul(a0_.h[0], es0.h[0]);                            \
            f32x2 v01 = pkmul(a0_.h[1], es0.h[1]);                            \
            f32x2 v10 = pkmul(a1_.h[0], es1.h[0]);                            \
            f32x2 v11 = pkmul(a1_.h[1], es1.h[1]);                            \
            f32x2 v20 = pkmul(a2_.h[0], es2.h[0]);                            \
            f32x2 v21 = pkmul(a2_.h[1], es2.h[1]);                            \
            unsigned w0 = pk2a(v00[0], v00[1]);                               \
            unsigned w1 = pk2a(v01[0], v01[1]);                               \
            unsigned w2 = pk2a(v10[0], v10[1]);                               \
            unsigned w3 = pk2a(v11[0], v11[1]);                               \
            unsigned w4 = pk2a(v20[0], v20[1]);                               \
            unsigned w5 = pk2a(v21[0], v21[1]);                               \
            if (G_) {                                                         \
                Bf[nt][0].u[0] = jk ? Bf[nt][0].u[0] : w0;                    \
                Bf[nt][0].u[1] = jk ? Bf[nt][0].u[1] : w1;                    \
                Bf[nt][0].u[2] = jk ? Bf[nt][0].u[2] : w2;                    \
                Bf[nt][0].u[3] = jk ? Bf[nt][0].u[3] : w3;                    \
                Bf[nt][1].u[0] = jk ? Bf[nt][1].u[0] : w4;                    \
                Bf[nt][1].u[1] = jk ? Bf[nt][1].u[1] : w5;                    \
            } else {                                                          \
                Bf[nt][0].u[0] = w0; Bf[nt][0].u[1] = w1;                     \
                Bf[nt][0].u[2] = w2; Bf[nt][0].u[3] = w3;                     \
                Bf[nt][1].u[0] = w4; Bf[nt][1].u[1] = w5;                     \
            }                                                                 \
            Bf[nt][1].u[2] = 0u; Bf[nt][1].u[3] = 0u;                         \
        }                                                                     \
        par ^= 1;                                                             \
    }

    int par = 0;
    if (nsteps > 0) {
        // eL for step t0; ring pf[j]=row(t0+j) j=1..7, pf[0]=row(t0+8), clamped
        if (lane < KK) eLs[0][lane] = __expf(lg_b[t0 * KK + jj]);
        float pf[8];
        #pragma unroll
        for (int j = 1; j < 8; ++j) {
            int rj = t0 + j; if (rj > TT - 1) rj = TT - 1;
            pf[j] = lg_b[rj * KK + jj];
        }
        { int rj = t0 + 8; if (rj > TT - 1) rj = TT - 1; pf[0] = lg_b[rj * KK + jj]; }

        const int nchunks = (nsteps + 7) / 8;
        #pragma unroll 1
        for (int cs = 0; cs < nchunks - 1; ++cs) {
            STEP(0, false) STEP(1, false) STEP(2, false) STEP(3, false)
            STEP(4, false) STEP(5, false) STEP(6, false) STEP(7, false)
        }
        {   // last chunk: junk-guarded (freezes Bf/sg for i >= nsteps)
            const int cs = nchunks - 1;
            STEP(0, true) STEP(1, true) STEP(2, true) STEP(3, true)
            STEP(4, true) STEP(5, true) STEP(6, true) STEP(7, true)
        }
    }
#undef STEP

    // ---- epilogue: stage Bf (= final Q, bf16) to LDS, then linear store ----
    #pragma unroll
    for (int nt = 0; nt < 3; ++nt) {
        ushort_t* basep = &Qst[(16 * nt + c) * KP];
        *(unsigned*)&basep[4 * g]          = Bf[nt][0].u[0];
        *(unsigned*)&basep[4 * g + 2]      = Bf[nt][0].u[1];
        *(unsigned*)&basep[16 + 4 * g]     = Bf[nt][0].u[2];
        *(unsigned*)&basep[16 + 4 * g + 2] = Bf[nt][0].u[3];
        *(unsigned*)&basep[32 + 4 * g]     = Bf[nt][1].u[0];
        *(unsigned*)&basep[32 + 4 * g + 2] = Bf[nt][1].u[1];
    }
    __syncthreads();

    // Qout[job][m][n] = Q[m][n] = Qst[n*KP + m]; lane = m.
    if (lane < KK) {
        const int m = lane;
        unsigned w[24];
        #pragma unroll
        for (int np = 0; np < 24; ++np) {
            unsigned lo = Qst[(2 * np)     * KP + m];
            unsigned hi = Qst[(2 * np + 1) * KP + m];
            w[np] = (hi << 16) | lo;
        }
        ushort_t* dst = Qout + (size_t)job * (KK * KK) + m * KK;
        #pragma unroll
        for (int i4 = 0; i4 < 6; ++i4) {
            uint4 o; o.x = w[4*i4]; o.y = w[4*i4+1]; o.z = w[4*i4+2]; o.w = w[4*i4+3];
            *(uint4*)&dst[8 * i4] = o;
        }
    }
    if (lane == 0) sigout[job] = sg;
}

// ---------------- Kernel 2: per-batch combine + scores (proven round-5) ----
__global__ __launch_bounds__(64) void crf_comb_kernel(
    const float* __restrict__ logits, const float* __restrict__ trans,
    const int* __restrict__ targets, const int* __restrict__ lens,
    const ushort_t* __restrict__ Qall, const float* __restrict__ sig,
    float* __restrict__ out)
{
    const int b = blockIdx.x, lane = threadIdx.x;
    const int jj = (lane < KK) ? lane : 0;
    const int L = lens[b];

    __shared__ float s_trans[KK * KK];
    for (int k = lane; k < KK * KK; k += 64) s_trans[k] = trans[k];
    __syncthreads();

    const float* lg_b = logits  + (size_t)b * TT * KK;
    const int*   tg_b = targets + (size_t)b * TT;

    float ub = 0.f;
    #pragma unroll 4
    for (int t = lane; t < TT; t += 64) {
        if (t < L) {
            int tg = tg_b[t];
            ub += lg_b[t * KK + tg];
            if (t >= 1) { int tp = tg_b[t - 1]; ub += s_trans[tp * KK + tg]; }
        }
    }
    #pragma unroll
    for (int d = 32; d >= 1; d >>= 1) ub += __shfl_xor(ub, d, 64);

    float log_norm = 0.f;
    if (L > 0) {
        float a0 = lg_b[jj];
        float M  = rlf(a0, 0);
        float s  = (lane < KK) ? __expf(a0 - M) : 0.f;
        int nf = (L >= 2) ? (L - 1) / SEG : 0;
        if (nf > NFULL) nf = NFULL;

        for (int ci = 0; ci <= nf; ++ci) {           // full segments, then tail
            const int job = b * 16 + ((ci < nf) ? ci : NFULL);
            const ushort_t* Qr = Qall + (size_t)job * (KK * KK) + jj * KK;
            unsigned rw[24];
            #pragma unroll
            for (int i4 = 0; i4 < 6; ++i4) {
                uint4 v = *(const uint4*)&Qr[8 * i4];
                rw[4*i4] = v.x; rw[4*i4+1] = v.y; rw[4*i4+2] = v.z; rw[4*i4+3] = v.w;
            }
            float acc = 0.f;
            #pragma unroll
            for (int ip = 0; ip < 24; ++ip) {
                unsigned u = rw[ip];
                float q0 = __uint_as_float(u << 16);
                float q1 = __uint_as_float(u & 0xFFFF0000u);
                acc = fmaf(rlf(s, 2 * ip),     q0, acc);
                acc = fmaf(rlf(s, 2 * ip + 1), q1, acc);
            }
            float r  = rlf(acc, 0);
            float rr = __builtin_amdgcn_rcpf(r);
            s = (lane < KK) ? acc * rr : 0.f;
            M += __logf(r) + sig[job];
        }

        float ssum = (lane < KK) ? s : 0.f;
        #pragma unroll
        for (int d = 32; d >= 1; d >>= 1) ssum += __shfl_xor(ssum, d, 64);
        log_norm = M + __logf(ssum);
    }

    if (lane == 0) out[b] = (L <= 0) ? 0.f : (ub - log_norm);
}

// ---------------- Round-3 fallback (ws too small) ----------------
__global__ __launch_bounds__(64) void crf_fwd_fallback(
    const float* __restrict__ logits, const float* __restrict__ trans,
    const int* __restrict__ targets, const int* __restrict__ lens,
    float* __restrict__ out)
{
    const int b = blockIdx.x, lane = threadIdx.x;
    const int jj = (lane < KK) ? lane : 0;
    const int L = lens[b];
    __shared__ float s_trans[KK * KK];
    for (int k = lane; k < KK * KK; k += 64) s_trans[k] = trans[k];
    float et[KK];
    #pragma unroll
    for (int i = 0; i < KK; ++i) et[i] = __expf(trans[i * KK + jj]);
    __syncthreads();
    const float* lg_b = logits + (size_t)b * TT * KK;
    const int* tg_b = targets + (size_t)b * TT;
    float ub = 0.f;
    for (int t = lane; t < TT; t += 64) {
        if (t < L) {
            int tg = tg_b[t];
            ub += lg_b[t * KK + tg];
            if (t >= 1) { int tp = tg_b[t - 1]; ub += s_trans[tp * KK + tg]; }
        }
    }
    #pragma unroll
    for (int d = 32; d >= 1; d >>= 1) ub += __shfl_xor(ub, d, 64);
    float a0 = lg_b[jj];
    float M = rlf(a0, 0);
    float s = (lane < KK) ? __expf(a0 - M) : 0.f;
    float sC = s, MC = M;
    const int Lm1 = L - 1;
    float pf[8];
    #pragma unroll
    for (int u = 0; u < 8; ++u) pf[u] = lg_b[(1 + u) * KK + jj];
    #pragma unroll 1
    for (int cc = 0; cc < 256; ++cc) {
        #pragma unroll
        for (int u = 0; u < 8; ++u) {
            const int t = 1 + cc * 8 + u;
            float lg = pf[u];
            int nrow = t + 8; if (nrow > TT - 1) nrow = TT - 1;
            pf[u] = lg_b[nrow * KK + jj];
            float eL = __expf(lg);
            float ac0 = 0.f, ac1 = 0.f, ac2 = 0.f, ac3 = 0.f;
            #pragma unroll
            for (int i = 0; i < KK; i += 4) {
                float s0 = rlf(s, i), s1 = rlf(s, i+1), s2 = rlf(s, i+2), s3 = rlf(s, i+3);
                ac0 = fmaf(s0, et[i], ac0);   ac1 = fmaf(s1, et[i+1], ac1);
                ac2 = fmaf(s2, et[i+2], ac2); ac3 = fmaf(s3, et[i+3], ac3);
            }
            float e = ((ac0 + ac1) + (ac2 + ac3)) * eL;
            bool cap = (t == Lm1);
            sC = cap ? e : sC;  MC = cap ? M : MC;
            float r = rlf(e, 0);
            s = e * __builtin_amdgcn_rcpf(r);
            M += __logf(r);
        }
    }
    float ssum = (lane < KK) ? sC : 0.f;
    #pragma unroll
    for (int d = 32; d >= 1; d >>= 1) ssum += __shfl_xor(ssum, d, 64);
    float log_norm = MC + __logf(ssum);
    if (lane == 0) out[b] = (L <= 0) ? 0.f : (ub - log_norm);
}

extern "C" void kernel_launch(void* const* d_in, const int* in_sizes, int n_in,
                              void* d_out, int out_size, void* d_ws, size_t ws_size,
                              hipStream_t stream) {
    const float* logits  = (const float*)d_in[0];
    const float* trans   = (const float*)d_in[1];
    const int*   targets = (const int*)  d_in[2];
    const int*   lens    = (const int*)  d_in[3];
    float*       out     = (float*)d_out;
    const int B = in_sizes[3];

    const size_t qbytes = (size_t)B * 16 * KK * KK * sizeof(ushort_t);
    const size_t need   = qbytes + (size_t)B * 16 * sizeof(float);
    if (ws_size >= need) {
        ushort_t* Qout = (ushort_t*)d_ws;
        float*    sig  = (float*)((char*)d_ws + qbytes);
        crf_seg_kernel<<<dim3(B, 16), 64, 0, stream>>>(logits, trans, lens, Qout, sig);
        crf_comb_kernel<<<B, 64, 0, stream>>>(logits, trans, targets, lens, Qout, sig, out);
    } else {
        crf_fwd_fallback<<<B, 64, 0, stream>>>(logits, trans, targets, lens, out);
    }
}